// Round 2
// baseline (3187.568 us; speedup 1.0000x reference)
//
#include <hip/hip_runtime.h>

// GRU scan, persistent kernel. B=512, S=1024, I=64, H=256, G=768, NC=10.
// 32 WGs x 512 threads. Block bg owns batch rows [16bg,16bg+16).
// Wave w owns h-cols [32w,32w+32) -> gate col-tiles {2w,2w+1,16+2w,17+2w,32+2w,33+2w}.
// R2: 5 Wh tiles resident in regs (160 VGPR), 6th tile + all Wx B-frags re-read
// from L2 each step (bf16 frags pre-staged in d_ws); x(t+1) reg-prefetched at
// step start. LDS = h ping-pong (16K) + x ping-pong (4K) only.

typedef short v8s __attribute__((ext_vector_type(8)));   // 8 bf16
typedef float f32x4 __attribute__((ext_vector_type(4)));

#define LDS_H    0
#define LDS_X    16384
#define LDS_SIZE 20480
#define WS_WXF_FRAGS (96 * 64)                 // 96 frags * 64 lanes (v8s units)
#define WS_WH6_FRAGS (64 * 64)
#define WS_NEED ((WS_WXF_FRAGS + WS_WH6_FRAGS) * 16)  // 160 KB

__device__ __forceinline__ unsigned short f2b(float f) {
    unsigned int u = __float_as_uint(f);
    u += 0x7FFFu + ((u >> 16) & 1u);       // RNE
    return (unsigned short)(u >> 16);
}
__device__ __forceinline__ float b2f(unsigned short h) {
    return __uint_as_float(((unsigned int)h) << 16);
}
__device__ __forceinline__ v8s cvt8(f32x4 a, f32x4 b) {
    v8s r;
#pragma unroll
    for (int j = 0; j < 4; ++j) { r[j] = (short)f2b(a[j]); r[4 + j] = (short)f2b(b[j]); }
    return r;
}
__device__ __forceinline__ float rcpf(float v) {
#if __has_builtin(__builtin_amdgcn_rcpf)
    return __builtin_amdgcn_rcpf(v);
#else
    return 1.0f / v;
#endif
}
__device__ __forceinline__ float sigm(float v) {
    float e = __expf(-fmaxf(v, -30.0f));
    return rcpf(1.0f + e);
}
__device__ __forceinline__ float tanh_(float v) {
    float vc = fmaxf(fminf(v, 30.0f), -30.0f);
    float e = __expf(-2.0f * vc);
    return (1.0f - e) * rcpf(1.0f + e);
}
__device__ __forceinline__ f32x4 MF(v8s a, v8s b, f32x4 c) {
    return __builtin_amdgcn_mfma_f32_16x16x32_bf16(a, b, c, 0, 0, 0);
}

// A-frag order index for element (row, k): u16 units
__device__ __forceinline__ int fidx(int row, int k) {
    return ((k >> 5) << 9) + ((((k >> 3) & 3) << 4) + row) * 8 + (k & 7);
}

template<bool PRE>
__global__ __launch_bounds__(512, 2) void gru_scan(
    const float* __restrict__ x, const float* __restrict__ Wx,
    const float* __restrict__ Wh, const float* __restrict__ bias,
    const float* __restrict__ fcw, const float* __restrict__ fcb,
    float* __restrict__ out, v8s* __restrict__ wsf)
{
    extern __shared__ char lds[];
    char* hl = lds + LDS_H;
    char* xl = lds + LDS_X;

    const int tid = threadIdx.x;
    const int w = tid >> 6, l = tid & 63;
    const int cl = l & 15, kg = l >> 4;
    const int b0 = blockIdx.x << 4;

    int tiles[6] = {2 * w, 2 * w + 1, 16 + 2 * w, 17 + 2 * w, 32 + 2 * w, 33 + 2 * w};

    v8s* wxf = wsf;                       // [96 frags][64 lanes]
    v8s* wh6 = wsf + WS_WXF_FRAGS;        // [8 waves][8 ks][64 lanes]

    if (PRE) {
        // stage Wx B-frags (96) + this wave's 6th Wh tile frags (8) into d_ws.
        // Every block writes the SAME bytes -> reads always follow own writes.
        for (int fid = w; fid < 96; fid += 8) {
            int ct = fid >> 1, k2 = fid & 1;
            const float* src = Wx + (size_t)(ct * 16 + cl) * 64 + k2 * 32 + kg * 8;
            wxf[fid * 64 + l] = cvt8(*(const f32x4*)src, *(const f32x4*)(src + 4));
        }
        const float* srcb = Wh + (size_t)((33 + 2 * w) * 16 + cl) * 256 + kg * 8;
#pragma unroll
        for (int ks = 0; ks < 8; ++ks)
            wh6[(w * 8 + ks) * 64 + l] =
                cvt8(*(const f32x4*)(srcb + ks * 32), *(const f32x4*)(srcb + ks * 32 + 4));
    }

    auto WH6 = [&](int ks) -> v8s {
        if (PRE) return wh6[(w * 8 + ks) * 64 + l];
        const float* s = Wh + (size_t)((33 + 2 * w) * 16 + cl) * 256 + ks * 32 + kg * 8;
        return cvt8(*(const f32x4*)s, *(const f32x4*)(s + 4));
    };
    auto WXF = [&](int fid) -> v8s {
        if (PRE) return wxf[fid * 64 + l];
        int ct = fid >> 1, k2 = fid & 1;
        const float* s = Wx + (size_t)(ct * 16 + cl) * 64 + k2 * 32 + kg * 8;
        return cvt8(*(const f32x4*)s, *(const f32x4*)(s + 4));
    };

    // ---- resident Wh B-fragments, tiles 0..4 only: 160 VGPRs ----
    v8s whB[5][8];
#pragma unroll
    for (int tt = 0; tt < 5; ++tt) {
        const float* src = Wh + (size_t)(tiles[tt] * 16 + cl) * 256 + kg * 8;
#pragma unroll
        for (int ks = 0; ks < 8; ++ks) {
            f32x4 a = *(const f32x4*)(src + ks * 32);
            f32x4 b = *(const f32x4*)(src + ks * 32 + 4);
            whB[tt][ks] = cvt8(a, b);
        }
    }

    // ---- bias registers ----
    float brv[2], bzv[2], bhv[2];
#pragma unroll
    for (int p = 0; p < 2; ++p) {
        int ch = (w << 5) + (p << 4) + cl;
        brv[p] = bias[ch];
        bzv[p] = bias[256 + ch];
        bhv[p] = bias[512 + ch];
    }

    // ---- h0 = 0 (buffer 0), stage x_0 ----
    for (int i = tid; i < 2048; i += 512) ((unsigned int*)hl)[i] = 0u;
    const int xr = tid >> 5, xc = (tid & 31) << 1;
    const int xidx = fidx(xr, xc);                    // even -> u32 aligned
    const float* xp = x + (((size_t)(b0 + xr)) << 16) + xc;
    {
        unsigned int pk = (unsigned int)f2b(xp[0]) | ((unsigned int)f2b(xp[1]) << 16);
        *(unsigned int*)(xl + xidx * 2) = pk;
    }
    xp += 64;                                          // points at t=1

    // ================= scan =================
    for (int t = 0; t < 1024; ++t) {
        __syncthreads();
        const int cur = t & 1;
        const v8s* hb = (const v8s*)(hl + cur * 8192);
        const v8s* xb = (const v8s*)(xl + cur * 2048);

        // reg-prefetch x(t+1) (hidden under the whole step)
        float xv0 = 0.0f, xv1 = 0.0f;
        if (t < 1023) { xv0 = xp[0]; xv1 = xp[1]; xp += 64; }

        // acc: 0,1=r  2,3=z  4,5=h_h(n)  6,7=i_h(n)
        f32x4 acc[8];
#pragma unroll
        for (int i = 0; i < 8; ++i) acc[i] = f32x4{0.0f, 0.0f, 0.0f, 0.0f};

        // ---- Wh phase: 5 reg tiles + tile5 streamed from L2 ----
        v8s f[8];
        f[0] = WH6(0); f[1] = WH6(1);
#pragma unroll
        for (int ks = 0; ks < 8; ++ks) {
            if (ks < 6) f[ks + 2] = WH6(ks + 2);
            v8s a = hb[(ks << 6) + l];
            acc[0] = MF(a, whB[0][ks], acc[0]);
            acc[1] = MF(a, whB[1][ks], acc[1]);
            acc[2] = MF(a, whB[2][ks], acc[2]);
            acc[3] = MF(a, whB[3][ks], acc[3]);
            acc[4] = MF(a, whB[4][ks], acc[4]);
            acc[5] = MF(a, f[ks], acc[5]);
        }

        // ---- x phase: B-frags streamed from L2 ----
#pragma unroll
        for (int k2 = 0; k2 < 2; ++k2) {
            v8s ax = xb[(k2 << 6) + l];
            acc[0] = MF(ax, WXF(tiles[0] * 2 + k2), acc[0]);
            acc[1] = MF(ax, WXF(tiles[1] * 2 + k2), acc[1]);
            acc[2] = MF(ax, WXF(tiles[2] * 2 + k2), acc[2]);
            acc[3] = MF(ax, WXF(tiles[3] * 2 + k2), acc[3]);
            acc[6] = MF(ax, WXF(tiles[4] * 2 + k2), acc[6]);
            acc[7] = MF(ax, WXF(tiles[5] * 2 + k2), acc[7]);
        }

        // ---- elementwise GRU update -> other h buffer ----
        const unsigned short* hc16 = (const unsigned short*)hb;
        unsigned short* hn16 = (unsigned short*)(hl + (cur ^ 1) * 8192);
#pragma unroll
        for (int p = 0; p < 2; ++p) {
            int ch = (w << 5) + (p << 4) + cl;
            int chbase = ((ch >> 5) << 9) + (((ch >> 3) & 3) << 7) + (ch & 7);
#pragma unroll
            for (int i = 0; i < 4; ++i) {
                int row = (kg << 2) + i;
                int idx = chbase + (row << 3);
                float rg = sigm(acc[p][i] + brv[p]);
                float zg = sigm(acc[2 + p][i] + bzv[p]);
                float ng = tanh_(acc[6 + p][i] + bhv[p] + rg * acc[4 + p][i]);
                float hold = b2f(hc16[idx]);
                float hy = ng + zg * (hold - ng);
                hn16[idx] = f2b(hy);
            }
        }

        // ---- stage prefetched x(t+1) into other x buffer ----
        if (t < 1023) {
            unsigned int pk = (unsigned int)f2b(xv0) | ((unsigned int)f2b(xv1) << 16);
            *(unsigned int*)(xl + (cur ^ 1) * 2048 + xidx * 2) = pk;
        }
    }

    __syncthreads();
    // ---- logits: hT (buffer 0) @ fc_w.T + fc_b ----
    const unsigned short* hf = (const unsigned short*)hl;
    if (tid < 160) {
        int row = tid / 10, cls = tid - row * 10;
        float s = fcb[cls];
        const float* wrow = fcw + cls * 256;
        for (int k = 0; k < 256; ++k)
            s += b2f(hf[fidx(row, k)]) * wrow[k];
        out[(b0 + row) * 10 + cls] = s;
    }
}

extern "C" void kernel_launch(void* const* d_in, const int* in_sizes, int n_in,
                              void* d_out, int out_size, void* d_ws, size_t ws_size,
                              hipStream_t stream) {
    const float* x    = (const float*)d_in[0];
    const float* Wx   = (const float*)d_in[1];
    const float* Wh   = (const float*)d_in[2];
    const float* bias = (const float*)d_in[3];
    const float* fcw  = (const float*)d_in[4];
    const float* fcb  = (const float*)d_in[5];

    if (ws_size >= (size_t)WS_NEED) {
        gru_scan<true><<<dim3(32), dim3(512), LDS_SIZE, stream>>>(
            x, Wx, Wh, bias, fcw, fcb, (float*)d_out, (v8s*)d_ws);
    } else {
        gru_scan<false><<<dim3(32), dim3(512), LDS_SIZE, stream>>>(
            x, Wx, Wh, bias, fcw, fcb, (float*)d_out, (v8s*)d_ws);
    }
}

// Round 3
// 2615.896 us; speedup vs baseline: 1.2185x; 1.2185x over previous
//
#include <hip/hip_runtime.h>

// GRU scan, persistent kernel. B=512, S=1024, I=64, H=256, G=768, NC=10.
// 32 WGs x 512 threads. Block bg owns batch rows [16bg,16bg+16).
// Wave w owns h-cols [32w,32w+32) -> gate col-tiles {2w,2w+1,16+2w,17+2w,32+2w,33+2w}.
// R3 register budget (the R1/R2 lesson): arch-VGPR pinned at 128 by the
// allocator, leaving exactly 128 AGPRs for resident weights at launch_bounds
// (512,2). So: 4 Wh tiles (r+z) resident = 128 regs EXACTLY; the n-gate Wh
// (16 tiles, 128KB) lives in LDS as pre-swizzled frags; Wx frags stream from
// L2 (d_ws) but are loaded at the TOP of each step (consumed ~1900 cyc later).

typedef short v8s __attribute__((ext_vector_type(8)));   // 8 bf16
typedef float f32x4 __attribute__((ext_vector_type(4)));

#define LDS_WHN  0          // 16 tiles * 8 ks * 64 lanes * 16B = 131072
#define LDS_H    131072     // 2 * 8192 ping-pong
#define LDS_X    147456     // 2 * 2048 ping-pong
#define LDS_SIZE 151552

#define WS_NEED (96 * 64 * 16)   // Wx frags in d_ws: 98304 B

__device__ __forceinline__ unsigned short f2b(float f) {
    unsigned int u = __float_as_uint(f);
    u += 0x7FFFu + ((u >> 16) & 1u);       // RNE
    return (unsigned short)(u >> 16);
}
__device__ __forceinline__ float b2f(unsigned short h) {
    return __uint_as_float(((unsigned int)h) << 16);
}
__device__ __forceinline__ v8s cvt8(f32x4 a, f32x4 b) {
    v8s r;
#pragma unroll
    for (int j = 0; j < 4; ++j) { r[j] = (short)f2b(a[j]); r[4 + j] = (short)f2b(b[j]); }
    return r;
}
__device__ __forceinline__ float rcpf(float v) {
#if __has_builtin(__builtin_amdgcn_rcpf)
    return __builtin_amdgcn_rcpf(v);
#else
    return 1.0f / v;
#endif
}
__device__ __forceinline__ float sigm(float v) {
    float e = __expf(-fmaxf(v, -30.0f));
    return rcpf(1.0f + e);
}
__device__ __forceinline__ float tanh_(float v) {
    float vc = fmaxf(fminf(v, 30.0f), -30.0f);
    float e = __expf(-2.0f * vc);
    return (1.0f - e) * rcpf(1.0f + e);
}
__device__ __forceinline__ f32x4 MF(v8s a, v8s b, f32x4 c) {
    return __builtin_amdgcn_mfma_f32_16x16x32_bf16(a, b, c, 0, 0, 0);
}

// A-frag order index for element (row, k): u16 units
__device__ __forceinline__ int fidx(int row, int k) {
    return ((k >> 5) << 9) + ((((k >> 3) & 3) << 4) + row) * 8 + (k & 7);
}

template<bool PRE>
__global__ __launch_bounds__(512, 2) void gru_scan(
    const float* __restrict__ x, const float* __restrict__ Wx,
    const float* __restrict__ Wh, const float* __restrict__ bias,
    const float* __restrict__ fcw, const float* __restrict__ fcb,
    float* __restrict__ out, v8s* __restrict__ wxf)
{
    extern __shared__ char lds[];
    v8s* whn = (v8s*)(lds + LDS_WHN);       // [16 tiles * 8 ks][64 lanes]
    char* hl = lds + LDS_H;
    char* xl = lds + LDS_X;

    const int tid = threadIdx.x;
    const int w = tid >> 6, l = tid & 63;
    const int cl = l & 15, kg = l >> 4;
    const int b0 = blockIdx.x << 4;

    const int tiles[6] = {2 * w, 2 * w + 1, 16 + 2 * w, 17 + 2 * w, 32 + 2 * w, 33 + 2 * w};

    if (PRE) {
        // stage Wx B-frags (96) into d_ws. Every block writes the SAME bytes,
        // then reads follow its own writes (same-XCD L2) after __syncthreads.
        for (int fid = w; fid < 96; fid += 8) {
            int ct = fid >> 1, k2 = fid & 1;
            const float* src = Wx + (size_t)(ct * 16 + cl) * 64 + k2 * 32 + kg * 8;
            wxf[fid * 64 + l] = cvt8(*(const f32x4*)src, *(const f32x4*)(src + 4));
        }
    }
    auto WXF = [&](int fid) -> v8s {
        if (PRE) return wxf[fid * 64 + l];
        int ct = fid >> 1, k2 = fid & 1;
        const float* s = Wx + (size_t)(ct * 16 + cl) * 64 + k2 * 32 + kg * 8;
        return cvt8(*(const f32x4*)s, *(const f32x4*)(s + 4));
    };

    // ---- n-gate Wh (tiles 32..47) -> LDS as frags: 128 frags of 1KB ----
    for (int f = w; f < 128; f += 8) {
        int t5 = f >> 3, ks = f & 7;
        const float* src = Wh + (size_t)(512 + t5 * 16 + cl) * 256 + ks * 32 + kg * 8;
        whn[f * 64 + l] = cvt8(*(const f32x4*)src, *(const f32x4*)(src + 4));
    }

    // ---- resident Wh B-frags, r+z tiles only: EXACTLY 128 regs ----
    v8s whB[4][8];
#pragma unroll
    for (int tt = 0; tt < 4; ++tt) {
        const float* src = Wh + (size_t)(tiles[tt] * 16 + cl) * 256 + kg * 8;
#pragma unroll
        for (int ks = 0; ks < 8; ++ks) {
            f32x4 a = *(const f32x4*)(src + ks * 32);
            f32x4 b = *(const f32x4*)(src + ks * 32 + 4);
            whB[tt][ks] = cvt8(a, b);
        }
    }

    // ---- bias registers ----
    float brv[2], bzv[2], bhv[2];
#pragma unroll
    for (int p = 0; p < 2; ++p) {
        int ch = (w << 5) + (p << 4) + cl;
        brv[p] = bias[ch];
        bzv[p] = bias[256 + ch];
        bhv[p] = bias[512 + ch];
    }

    // ---- h0 = 0 (buffer 0), stage x_0 ----
    for (int i = tid; i < 2048; i += 512) ((unsigned int*)hl)[i] = 0u;
    const int xr = tid >> 5, xc = (tid & 31) << 1;
    const int xidx = fidx(xr, xc);                    // even -> u32 aligned
    const float* xp = x + (((size_t)(b0 + xr)) << 16) + xc;
    {
        unsigned int pk = (unsigned int)f2b(xp[0]) | ((unsigned int)f2b(xp[1]) << 16);
        *(unsigned int*)(xl + xidx * 2) = pk;
    }
    xp += 64;                                          // points at t=1

    const int wn0 = (2 * w) * 8;                       // LDS frag base, tile 32+2w
    const int wn1 = (2 * w + 1) * 8;                   // tile 33+2w

    // ================= scan =================
    for (int t = 0; t < 1024; ++t) {
        __syncthreads();
        const int cur = t & 1;
        const v8s* hb = (const v8s*)(hl + cur * 8192);
        const v8s* xb = (const v8s*)(xl + cur * 2048);

        // issue ALL long-latency loads up front (consumed at end of step):
        // x(t+1) for staging, and the 12 Wx B-frags for the x-phase.
        float xv0 = 0.0f, xv1 = 0.0f;
        if (t < 1023) { xv0 = xp[0]; xv1 = xp[1]; xp += 64; }
        v8s wxr[12];
#pragma unroll
        for (int tt = 0; tt < 6; ++tt) {
            wxr[tt * 2]     = WXF(tiles[tt] * 2);
            wxr[tt * 2 + 1] = WXF(tiles[tt] * 2 + 1);
        }

        // acc: 0,1=r  2,3=z  4,5=h_h(n)  6,7=i_h(n)
        f32x4 acc[8];
#pragma unroll
        for (int i = 0; i < 8; ++i) acc[i] = f32x4{0.0f, 0.0f, 0.0f, 0.0f};

        // ---- Wh phase: 4 reg tiles + 2 n-gate tiles from LDS ----
#pragma unroll
        for (int ks = 0; ks < 8; ++ks) {
            v8s a  = hb[(ks << 6) + l];
            v8s n0 = whn[(wn0 + ks) * 64 + l];
            v8s n1 = whn[(wn1 + ks) * 64 + l];
            acc[0] = MF(a, whB[0][ks], acc[0]);
            acc[1] = MF(a, whB[1][ks], acc[1]);
            acc[2] = MF(a, whB[2][ks], acc[2]);
            acc[3] = MF(a, whB[3][ks], acc[3]);
            acc[4] = MF(a, n0, acc[4]);
            acc[5] = MF(a, n1, acc[5]);
        }

        // ---- x phase: B-frags already in regs ----
#pragma unroll
        for (int k2 = 0; k2 < 2; ++k2) {
            v8s ax = xb[(k2 << 6) + l];
            acc[0] = MF(ax, wxr[0 + k2], acc[0]);
            acc[1] = MF(ax, wxr[2 + k2], acc[1]);
            acc[2] = MF(ax, wxr[4 + k2], acc[2]);
            acc[3] = MF(ax, wxr[6 + k2], acc[3]);
            acc[6] = MF(ax, wxr[8 + k2], acc[6]);
            acc[7] = MF(ax, wxr[10 + k2], acc[7]);
        }

        // ---- elementwise GRU update -> other h buffer ----
        const unsigned short* hc16 = (const unsigned short*)hb;
        unsigned short* hn16 = (unsigned short*)(hl + (cur ^ 1) * 8192);
#pragma unroll
        for (int p = 0; p < 2; ++p) {
            int ch = (w << 5) + (p << 4) + cl;
            int chbase = ((ch >> 5) << 9) + (((ch >> 3) & 3) << 7) + (ch & 7);
#pragma unroll
            for (int i = 0; i < 4; ++i) {
                int row = (kg << 2) + i;
                int idx = chbase + (row << 3);
                float rg = sigm(acc[p][i] + brv[p]);
                float zg = sigm(acc[2 + p][i] + bzv[p]);
                float ng = tanh_(acc[6 + p][i] + bhv[p] + rg * acc[4 + p][i]);
                float hold = b2f(hc16[idx]);
                float hy = ng + zg * (hold - ng);
                hn16[idx] = f2b(hy);
            }
        }

        // ---- stage prefetched x(t+1) into other x buffer ----
        if (t < 1023) {
            unsigned int pk = (unsigned int)f2b(xv0) | ((unsigned int)f2b(xv1) << 16);
            *(unsigned int*)(xl + (cur ^ 1) * 2048 + xidx * 2) = pk;
        }
    }

    __syncthreads();
    // ---- logits: hT (buffer 0) @ fc_w.T + fc_b ----
    const unsigned short* hf = (const unsigned short*)(hl);
    if (tid < 160) {
        int row = tid / 10, cls = tid - row * 10;
        float s = fcb[cls];
        const float* wrow = fcw + cls * 256;
        for (int k = 0; k < 256; ++k)
            s += b2f(hf[fidx(row, k)]) * wrow[k];
        out[(b0 + row) * 10 + cls] = s;
    }
}

extern "C" void kernel_launch(void* const* d_in, const int* in_sizes, int n_in,
                              void* d_out, int out_size, void* d_ws, size_t ws_size,
                              hipStream_t stream) {
    const float* x    = (const float*)d_in[0];
    const float* Wx   = (const float*)d_in[1];
    const float* Wh   = (const float*)d_in[2];
    const float* bias = (const float*)d_in[3];
    const float* fcw  = (const float*)d_in[4];
    const float* fcb  = (const float*)d_in[5];

    if (ws_size >= (size_t)WS_NEED) {
        (void)hipFuncSetAttribute((const void*)gru_scan<true>,
                                  hipFuncAttributeMaxDynamicSharedMemorySize, LDS_SIZE);
        gru_scan<true><<<dim3(32), dim3(512), LDS_SIZE, stream>>>(
            x, Wx, Wh, bias, fcw, fcb, (float*)d_out, (v8s*)d_ws);
    } else {
        (void)hipFuncSetAttribute((const void*)gru_scan<false>,
                                  hipFuncAttributeMaxDynamicSharedMemorySize, LDS_SIZE);
        gru_scan<false><<<dim3(32), dim3(512), LDS_SIZE, stream>>>(
            x, Wx, Wh, bias, fcw, fcb, (float*)d_out, (v8s*)d_ws);
    }
}